// Round 10
// baseline (25.849 us; speedup 1.0000x reference)
//
#include <hip/hip_runtime.h>
#include <cstdint>

// Ball query, cell-centric: queries grouped by grid cell; one block per cell
// stages the 27-cell candidate set into LDS once and serves all its queries.
// Membership decision replicates the numpy-f32 reference EXACTLY (round 5):
//   norms:   pure rn  n = rn(rn(xx + yy) + zz)         (ufunc passes)
//   dot:     FMA chain d = fma(z1,z2, fma(y1,y2, rn(x1*x2)))  (sgemm K-loop)
//   combine: pure rn  d2 = rn(rn(n1+n2) - rn(2*dot))
// hipcc defaults to -ffp-contract=fast which would fuse the plain-op chains:
// every kernel/function touching the decision carries
// #pragma clang fp contract(off); the dot uses explicit __fmaf_rn.
// DO NOT ALTER THIS CHAIN.
//
// Grid: 12^3 cells, cell 1/12 = 0.0833 > max accepted distance ~0.08000 =>
// for any query IN a cell, all FP-accepted neighbors lie in that cell's
// 27-neighborhood. Both p2 (search points) and p1 (queries) are counting-
// sorted into per-cell runs (NPART=4 striped partitions for build
// parallelism). Within-cell order is atomic-nondeterministic, but hit
// ranking is by original index -> outputs deterministic.
//
// Outputs (flat float32, concatenated):
//   [0          : N1*K)        mapping   (index as float; unfilled -> 0)
//   [N1*K       : N1*K+N1)     num_neighbors (min(count, K))
//   [N1*K+N1    : +N1*K*3)     gathered coords (unfilled -> 0)

#define BQ_K    32
#define BQ_N1   8192
#define BQ_N2   16384
#define GDIM    12
#define NCELLS  (GDIM * GDIM * GDIM)  // 1728
#define NPART   4
#define PPTS2   (BQ_N2 / NPART)       // 4096
#define PPTS1   (BQ_N1 / NPART)       // 2048
#define NRUNS   (27 * NPART)          // 108
#define CANDCAP 640                   // candidates/block cap (avg ~256, +24σ)
#define HITCAP  128                   // hits/query cap (avg ~35)

// d_ws layout (bytes):
#define WS_META2_OFF 0                          // uint[NCELLS*NPART]
#define WS_META1_OFF (NCELLS * NPART * 4)       // uint[NCELLS*NPART] (27648)
#define WS_SORT2_OFF (2 * NCELLS * NPART * 4)   // float4[BQ_N2] (55296, 16B ok)
#define WS_SORTQ_OFF (WS_SORT2_OFF + BQ_N2 * 16)  // int[BQ_N1] (317440)
#define WS_NEED      (WS_SORTQ_OFF + BQ_N1 * 4)   // 350208

__device__ __forceinline__ int bq_cell(float x, float y, float z) {
  int cx = min(max((int)(x * (float)GDIM), 0), GDIM - 1);
  int cy = min(max((int)(y * (float)GDIM), 0), GDIM - 1);
  int cz = min(max((int)(z * (float)GDIM), 0), GDIM - 1);
  return (cz * GDIM + cy) * GDIM + cx;
}

// Build BOTH grids: 4 workgroups, each owns striped partition p of p2 and p1.
// meta[cell*NPART+p] = (cnt<<16 | absolute_start); both fields fit 16 bits.
__global__ __launch_bounds__(1024) void bq_build_kernel(
    const float* __restrict__ p1, const float* __restrict__ p2,
    unsigned int* __restrict__ meta1, unsigned int* __restrict__ meta2,
    float4* __restrict__ sorted2, int* __restrict__ sortedq) {
  __shared__ int s_cnt[NCELLS];  // counts, then absolute cursors
  __shared__ int s_wave[16];
  const int t = threadIdx.x;
  const int lane = t & 63, wv = t >> 6;
  const int p = blockIdx.x;

  // ---- Phase A: p2 grid (4096 pts, 4/thread) ----
  for (int i = t; i < NCELLS; i += 1024) s_cnt[i] = 0;
  __syncthreads();
  float ax[4], ay[4], az[4];
  int ac[4];
#pragma unroll
  for (int k = 0; k < 4; ++k) {
    const int i = p * PPTS2 + k * 1024 + t;  // coalesced
    ax[k] = p2[i * 3 + 0];
    ay[k] = p2[i * 3 + 1];
    az[k] = p2[i * 3 + 2];
    ac[k] = bq_cell(ax[k], ay[k], az[k]);
    atomicAdd(&s_cnt[ac[k]], 1);
  }
  __syncthreads();
  {
    const int cell0 = t * 2;
    int c0 = 0, c1 = 0;
    if (cell0 < NCELLS) { c0 = s_cnt[cell0]; c1 = s_cnt[cell0 + 1]; }
    const int sum = c0 + c1;
    int inc = sum;
#pragma unroll
    for (int d = 1; d < 64; d <<= 1) {
      int v = __shfl_up(inc, d);
      if (lane >= d) inc += v;
    }
    if (lane == 63) s_wave[wv] = inc;
    __syncthreads();
    if (t == 0) {
      int r = 0;
      for (int w = 0; w < 16; ++w) { int v = s_wave[w]; s_wave[w] = r; r += v; }
    }
    __syncthreads();
    const int excl = s_wave[wv] + (inc - sum);
    if (cell0 < NCELLS) {
      const int st0 = p * PPTS2 + excl;
      const int st1 = st0 + c0;
      meta2[cell0 * NPART + p] = ((unsigned)c0 << 16) | (unsigned)st0;
      meta2[(cell0 + 1) * NPART + p] = ((unsigned)c1 << 16) | (unsigned)st1;
      s_cnt[cell0] = st0;
      s_cnt[cell0 + 1] = st1;
    }
  }
  __syncthreads();
#pragma unroll
  for (int k = 0; k < 4; ++k) {
    const int i = p * PPTS2 + k * 1024 + t;
    const int slot = atomicAdd(&s_cnt[ac[k]], 1);
    sorted2[slot] = make_float4(ax[k], ay[k], az[k], __int_as_float(i));
  }
  __syncthreads();

  // ---- Phase B: p1 (query) grid (2048 pts, 2/thread) ----
  for (int i = t; i < NCELLS; i += 1024) s_cnt[i] = 0;
  __syncthreads();
  int bc[2];
#pragma unroll
  for (int k = 0; k < 2; ++k) {
    const int i = p * PPTS1 + k * 1024 + t;
    const float x = p1[i * 3 + 0];
    const float y = p1[i * 3 + 1];
    const float z = p1[i * 3 + 2];
    bc[k] = bq_cell(x, y, z);
    atomicAdd(&s_cnt[bc[k]], 1);
  }
  __syncthreads();
  {
    const int cell0 = t * 2;
    int c0 = 0, c1 = 0;
    if (cell0 < NCELLS) { c0 = s_cnt[cell0]; c1 = s_cnt[cell0 + 1]; }
    const int sum = c0 + c1;
    int inc = sum;
#pragma unroll
    for (int d = 1; d < 64; d <<= 1) {
      int v = __shfl_up(inc, d);
      if (lane >= d) inc += v;
    }
    if (lane == 63) s_wave[wv] = inc;
    __syncthreads();
    if (t == 0) {
      int r = 0;
      for (int w = 0; w < 16; ++w) { int v = s_wave[w]; s_wave[w] = r; r += v; }
    }
    __syncthreads();
    const int excl = s_wave[wv] + (inc - sum);
    if (cell0 < NCELLS) {
      const int st0 = p * PPTS1 + excl;
      const int st1 = st0 + c0;
      meta1[cell0 * NPART + p] = ((unsigned)c0 << 16) | (unsigned)st0;
      meta1[(cell0 + 1) * NPART + p] = ((unsigned)c1 << 16) | (unsigned)st1;
      s_cnt[cell0] = st0;
      s_cnt[cell0 + 1] = st1;
    }
  }
  __syncthreads();
#pragma unroll
  for (int k = 0; k < 2; ++k) {
    const int i = p * PPTS1 + k * 1024 + t;
    const int slot = atomicAdd(&s_cnt[bc[k]], 1);
    sortedq[slot] = i;
  }
}

// Per-query full-scan fallback (exact round-5 semantics). Rare/never.
__device__ void bq_full_scan(const float* __restrict__ p2, int lane, float x1,
                             float y1, float z1, float n1, float rsq,
                             float* __restrict__ mapO, float* __restrict__ numO,
                             float* __restrict__ ptsO) {
#pragma clang fp contract(off)
  int filled = 0;
  for (int base = 0; base < BQ_N2; base += 64) {
    const int j = base + lane;
    const float x2 = p2[j * 3 + 0];
    const float y2 = p2[j * 3 + 1];
    const float z2 = p2[j * 3 + 2];
    const float n2 = (x2 * x2 + y2 * y2) + z2 * z2;
    float dot = x2 * x1;
    dot = __fmaf_rn(y1, y2, dot);
    dot = __fmaf_rn(z1, z2, dot);
    const float d2 = (n1 + n2) - 2.0f * dot;
    const bool within = (d2 <= rsq);
    const unsigned long long b = __ballot(within);
    if (b) {
      const int rank = (int)__popcll(b & ((1ull << lane) - 1ull));
      const int slot = filled + rank;
      if (within && slot < BQ_K) {
        mapO[slot] = (float)j;
        ptsO[slot * 3 + 0] = x2;
        ptsO[slot * 3 + 1] = y2;
        ptsO[slot * 3 + 2] = z2;
      }
      filled += (int)__popcll(b);
      if (filled >= BQ_K) { filled = BQ_K; break; }
    }
  }
  for (int s = filled + lane; s < BQ_K; s += 64) {
    mapO[s] = 0.0f;
    ptsO[s * 3 + 0] = 0.0f;
    ptsO[s * 3 + 1] = 0.0f;
    ptsO[s * 3 + 2] = 0.0f;
  }
  if (lane == 0) numO[0] = (float)filled;
}

// One block per cell; 4 waves share LDS-staged candidates, each wave serves
// queries iq = wid, wid+4, ... of the cell.
__global__ __launch_bounds__(256) void bq_query_kernel(
    const float* __restrict__ p1, const float* __restrict__ p2,
    const unsigned int* __restrict__ meta1,
    const unsigned int* __restrict__ meta2,
    const float4* __restrict__ sorted2, const int* __restrict__ sortedq,
    float* __restrict__ out) {
#pragma clang fp contract(off)
  const int t = threadIdx.x;
  const int lane = t & 63;
  const int wid = t >> 6;
  // XCD-chunked cell mapping: XCD k serves contiguous cells [k*216,(k+1)*216).
  const int b = blockIdx.x;
  const int cell = (b & 7) * (NCELLS / 8) + (b >> 3);

  // Query runs for this cell: one uint4.
  const uint4 m1 = *reinterpret_cast<const uint4*>(&meta1[cell * NPART]);
  const int qc0 = (int)(m1.x >> 16), qs0 = (int)(m1.x & 0xFFFFu);
  const int qc1 = (int)(m1.y >> 16), qs1 = (int)(m1.y & 0xFFFFu);
  const int qc2 = (int)(m1.z >> 16), qs2 = (int)(m1.z & 0xFFFFu);
  const int qc3 = (int)(m1.w >> 16), qs3 = (int)(m1.w & 0xFFFFu);
  const int qtot = qc0 + qc1 + qc2 + qc3;
  if (qtot == 0) return;  // block-uniform

  __shared__ unsigned int s_runmeta[NRUNS];  // (cnt<<16 | start)
  __shared__ int s_runpref[NRUNS];
  __shared__ int s_gidx[CANDCAP];
  __shared__ float4 s_cand[CANDCAP];
  __shared__ float4 s_hits[4][HITCAP];
  __shared__ int s_T;

  const int cx = cell % GDIM;
  const int cy = (cell / GDIM) % GDIM;
  const int cz = cell / (GDIM * GDIM);

  // Wave 0 sets up the 108-run candidate table metadata.
  if (wid == 0) {
    int c0 = 0, c1 = 0, c2 = 0, c3 = 0;
    int st0 = 0, st1 = 0, st2 = 0, st3 = 0;
    if (lane < 27) {
      const int nx = cx + (lane % 3) - 1;
      const int ny = cy + ((lane / 3) % 3) - 1;
      const int nz = cz + (lane / 9) - 1;
      if (nx >= 0 && nx < GDIM && ny >= 0 && ny < GDIM && nz >= 0 &&
          nz < GDIM) {
        const int cc = (nz * GDIM + ny) * GDIM + nx;
        const uint4 m2 =
            *reinterpret_cast<const uint4*>(&meta2[cc * NPART]);
        c0 = (int)(m2.x >> 16); st0 = (int)(m2.x & 0xFFFFu);
        c1 = (int)(m2.y >> 16); st1 = (int)(m2.y & 0xFFFFu);
        c2 = (int)(m2.z >> 16); st2 = (int)(m2.z & 0xFFFFu);
        c3 = (int)(m2.w >> 16); st3 = (int)(m2.w & 0xFFFFu);
      }
    }
    const int lsum = c0 + c1 + c2 + c3;
    int inc = lsum;
#pragma unroll
    for (int d = 1; d < 64; d <<= 1) {
      int v = __shfl_up(inc, d);
      if (lane >= d) inc += v;
    }
    const int pref0 = inc - lsum;
    if (lane < 27) {
      s_runmeta[lane * 4 + 0] = ((unsigned)c0 << 16) | (unsigned)st0;
      s_runmeta[lane * 4 + 1] = ((unsigned)c1 << 16) | (unsigned)st1;
      s_runmeta[lane * 4 + 2] = ((unsigned)c2 << 16) | (unsigned)st2;
      s_runmeta[lane * 4 + 3] = ((unsigned)c3 << 16) | (unsigned)st3;
      s_runpref[lane * 4 + 0] = pref0;
      s_runpref[lane * 4 + 1] = pref0 + c0;
      s_runpref[lane * 4 + 2] = pref0 + c0 + c1;
      s_runpref[lane * 4 + 3] = pref0 + c0 + c1 + c2;
    }
    if (lane == 63) s_T = inc;  // total candidates
  }
  __syncthreads();
  const int T = s_T;
  const bool fast = (T <= CANDCAP);

  if (fast) {
    // Materialize candidate global indices (thread r owns run r, avg 2.4).
    if (t < NRUNS) {
      const unsigned int rm = s_runmeta[t];
      const int rc = (int)(rm >> 16);
      const int rs = (int)(rm & 0xFFFFu);
      const int rp = s_runpref[t];
      for (int k = 0; k < rc; ++k) s_gidx[rp + k] = rs + k;
    }
    __syncthreads();
    // Stage candidates into LDS (one-shot, semi-coalesced gather).
    for (int s = t; s < T; s += 256) s_cand[s] = sorted2[s_gidx[s]];
    __syncthreads();
  }

  const float rsq = (float)(0.08 * 0.08);

  // Each wave serves queries wid, wid+4, ... (wave-uniform loop).
  for (int iq = wid; iq < qtot; iq += 4) {
    // Locate query's global index (wave-uniform scalar math).
    int g;
    if (iq < qc0) g = qs0 + iq;
    else if (iq < qc0 + qc1) g = qs1 + (iq - qc0);
    else if (iq < qc0 + qc1 + qc2) g = qs2 + (iq - qc0 - qc1);
    else g = qs3 + (iq - qc0 - qc1 - qc2);
    const int qidx = sortedq[g];

    const float x1 = p1[qidx * 3 + 0];
    const float y1 = p1[qidx * 3 + 1];
    const float z1 = p1[qidx * 3 + 2];
    const float n1 = (x1 * x1 + y1 * y1) + z1 * z1;  // pure rn (contract off)

    float* __restrict__ mapO = out + (size_t)qidx * BQ_K;
    float* __restrict__ numO = out + (size_t)BQ_N1 * BQ_K + qidx;
    float* __restrict__ ptsO =
        out + (size_t)BQ_N1 * BQ_K + BQ_N1 + (size_t)qidx * BQ_K * 3;

    if (!fast) {
      bq_full_scan(p2, lane, x1, y1, z1, n1, rsq, mapO, numO, ptsO);
      continue;
    }

    // Sweep LDS candidates.
    int H = 0;
    for (int s0 = 0; s0 < T; s0 += 64) {
      const int s = s0 + lane;
      bool within = false;
      float x2 = 0.f, y2 = 0.f, z2 = 0.f;
      int idx = 0;
      if (s < T) {
        const float4 pt = s_cand[s];
        x2 = pt.x; y2 = pt.y; z2 = pt.z;
        idx = __float_as_int(pt.w);
        // EXACT reference FP chain (round 5) — do not alter.
        const float n2 = (x2 * x2 + y2 * y2) + z2 * z2;
        float dot = x2 * x1;
        dot = __fmaf_rn(y1, y2, dot);
        dot = __fmaf_rn(z1, z2, dot);
        const float nsum = n1 + n2;
        const float twodot = 2.0f * dot;
        const float d2 = nsum - twodot;
        within = (d2 <= rsq);
      }
      const unsigned long long bal = __ballot(within);
      if (bal) {
        if (within) {
          const int pos = H + (int)__popcll(bal & ((1ull << lane) - 1ull));
          if (pos < HITCAP)
            s_hits[wid][pos] = make_float4(x2, y2, z2, __int_as_float(idx));
        }
        H += (int)__popcll(bal);
      }
    }

    if (H > HITCAP) {  // safety net; P ~ 0
      bq_full_scan(p2, lane, x1, y1, z1, n1, rsq, mapO, numO, ptsO);
      continue;
    }

    // Rank hits by original index (deterministic output).
    const int nh = min(H, BQ_K);
    float4 h0 = make_float4(0.f, 0.f, 0.f, __int_as_float(0x7fffffff));
    float4 h1 = h0;
    if (lane < H) h0 = s_hits[wid][lane];
    if (lane + 64 < H) h1 = s_hits[wid][lane + 64];
    const int i0 = __float_as_int(h0.w);
    const int i1 = __float_as_int(h1.w);
    int r0 = 0, r1 = 0;
    for (int j = 0; j < H; ++j) {  // broadcast LDS reads
      const int bj = __float_as_int(s_hits[wid][j].w);
      r0 += (bj < i0) ? 1 : 0;
      r1 += (bj < i1) ? 1 : 0;
    }
    if (lane < H && r0 < BQ_K) {
      mapO[r0] = (float)i0;
      ptsO[r0 * 3 + 0] = h0.x;
      ptsO[r0 * 3 + 1] = h0.y;
      ptsO[r0 * 3 + 2] = h0.z;
    }
    if (lane + 64 < H && r1 < BQ_K) {
      mapO[r1] = (float)i1;
      ptsO[r1 * 3 + 0] = h1.x;
      ptsO[r1 * 3 + 1] = h1.y;
      ptsO[r1 * 3 + 2] = h1.z;
    }
    for (int sF = nh + lane; sF < BQ_K; sF += 64) {
      mapO[sF] = 0.0f;
      ptsO[sF * 3 + 0] = 0.0f;
      ptsO[sF * 3 + 1] = 0.0f;
      ptsO[sF * 3 + 2] = 0.0f;
    }
    if (lane == 0) numO[0] = (float)nh;
  }
}

// Round-5 brute-force kernel, whole-problem fallback if ws too small.
__global__ __launch_bounds__(256) void bq_seq_kernel(
    const float* __restrict__ p1, const float* __restrict__ p2,
    float* __restrict__ out) {
#pragma clang fp contract(off)
  const int lane = threadIdx.x & 63;
  const int wave = threadIdx.x >> 6;
  const int q = blockIdx.x * 4 + wave;
  const float x1 = p1[q * 3 + 0], y1 = p1[q * 3 + 1], z1 = p1[q * 3 + 2];
  const float n1 = (x1 * x1 + y1 * y1) + z1 * z1;
  const float rsq = (float)(0.08 * 0.08);
  float* mapO = out + (size_t)q * BQ_K;
  float* numO = out + (size_t)BQ_N1 * BQ_K + q;
  float* ptsO = out + (size_t)BQ_N1 * BQ_K + BQ_N1 + (size_t)q * BQ_K * 3;
  bq_full_scan(p2, lane, x1, y1, z1, n1, rsq, mapO, numO, ptsO);
}

extern "C" void kernel_launch(void* const* d_in, const int* in_sizes, int n_in,
                              void* d_out, int out_size, void* d_ws,
                              size_t ws_size, hipStream_t stream) {
  const float* p1 = (const float*)d_in[0];
  const float* p2 = (const float*)d_in[1];
  float* out = (float*)d_out;

  if (ws_size < (size_t)WS_NEED) {
    bq_seq_kernel<<<BQ_N1 / 4, 256, 0, stream>>>(p1, p2, out);
    return;
  }

  char* ws = (char*)d_ws;
  unsigned int* meta2 = (unsigned int*)(ws + WS_META2_OFF);
  unsigned int* meta1 = (unsigned int*)(ws + WS_META1_OFF);
  float4* sorted2 = (float4*)(ws + WS_SORT2_OFF);
  int* sortedq = (int*)(ws + WS_SORTQ_OFF);

  bq_build_kernel<<<NPART, 1024, 0, stream>>>(p1, p2, meta1, meta2, sorted2,
                                              sortedq);
  bq_query_kernel<<<NCELLS, 256, 0, stream>>>(p1, p2, meta1, meta2, sorted2,
                                              sortedq, out);
}

// Round 11
// 21.098 us; speedup vs baseline: 1.2252x; 1.2252x over previous
//
#include <hip/hip_runtime.h>
#include <cstdint>

// Ball query via 4-way-partitioned spatial grid, 2 dispatches.
// == Round-8 structure (best: 20.8us) + packed meta ONLY (de-confounds r9) ==
// Membership decision replicates the numpy-f32 reference EXACTLY (round 5):
//   norms:   pure rn  n = rn(rn(xx + yy) + zz)         (ufunc passes)
//   dot:     FMA chain d = fma(z1,z2, fma(y1,y2, rn(x1*x2)))  (sgemm K-loop)
//   combine: pure rn  d2 = rn(rn(n1+n2) - rn(2*dot))
// hipcc's -ffp-contract=fast would fuse the plain-op chains -> compute kernels
// carry #pragma clang fp contract(off); the dot uses explicit __fmaf_rn.
// DO NOT ALTER THIS CHAIN.
//
// Grid: 12^3 cells, cell 1/12 = 0.0833 > max accepted distance ~0.08000 =>
// any FP-accepted neighbor lies in the 27-cell neighborhood. Points striped
// into P=4 contiguous partitions; partition p occupies sorted[p*4096..+4096).
// Per-(cell,part) metadata is ONE uint (cnt<<16 | start), part-minor:
// meta[cell*4+part] -> a query lane fetches its 2 runs with one aligned
// uint2 load. Query merges 108 (cell,part) runs; output is ranked by original
// index so atomic scatter order is irrelevant. Cells with AABB min-dist^2 >
// rsq*1.002 are pruned (margin 1.2e-5 >> FP slop ~1e-6; verified absmax 0
// rounds 8-10).
//
// Outputs (flat float32, concatenated):
//   [0          : N1*K)        mapping   (index as float; unfilled -> 0)
//   [N1*K       : N1*K+N1)     num_neighbors (min(count, K))
//   [N1*K+N1    : +N1*K*3)     gathered coords (unfilled -> 0)

#define BQ_K    32
#define BQ_N1   8192
#define BQ_N2   16384
#define GDIM    12
#define NCELLS  (GDIM * GDIM * GDIM)  // 1728
#define NPART   4
#define PPTS    (BQ_N2 / NPART)       // 4096 per partition
#define NPAIRS  (27 * NPART)          // 108
#define HITCAP  128                   // max hits on fast path (data max ~60)
#define GIDXCAP 512                   // max candidates on fast path (avg ~180)

// d_ws layout (bytes):
#define WS_META_OFF   0                      // uint[NCELLS*NPART] (27648)
#define WS_SORTED_OFF (NCELLS * NPART * 4)   // float4[BQ_N2] (27648: 16B ok)
#define WS_NEED       (WS_SORTED_OFF + BQ_N2 * 16)

__device__ __forceinline__ int bq_cell(float x, float y, float z) {
  int cx = min(max((int)(x * (float)GDIM), 0), GDIM - 1);
  int cy = min(max((int)(y * (float)GDIM), 0), GDIM - 1);
  int cz = min(max((int)(z * (float)GDIM), 0), GDIM - 1);
  return (cz * GDIM + cy) * GDIM + cx;
}

// Grid build: 4 workgroups, each builds its partition's sub-grid.
__global__ __launch_bounds__(1024) void bq_build_kernel(
    const float* __restrict__ p2, unsigned int* __restrict__ meta,
    float4* __restrict__ sorted) {
  __shared__ int s_cnt[NCELLS];  // counts, then absolute cursors
  __shared__ int s_wave[16];
  const int t = threadIdx.x;
  const int lane = t & 63, wv = t >> 6;
  const int p = blockIdx.x;
  const int pbase = p * PPTS;

  for (int i = t; i < NCELLS; i += 1024) s_cnt[i] = 0;
  __syncthreads();

  float px[4], py[4], pz[4];
  int pc[4];
#pragma unroll
  for (int k = 0; k < 4; ++k) {
    const int i = pbase + k * 1024 + t;  // coalesced
    px[k] = p2[i * 3 + 0];
    py[k] = p2[i * 3 + 1];
    pz[k] = p2[i * 3 + 2];
    pc[k] = bq_cell(px[k], py[k], pz[k]);
    atomicAdd(&s_cnt[pc[k]], 1);
  }
  __syncthreads();

  // Exclusive scan of s_cnt[1728]: 2 cells/thread (threads 0..863 active).
  const int cell0 = t * 2;
  int c0 = 0, c1 = 0;
  if (cell0 < NCELLS) {
    c0 = s_cnt[cell0];
    c1 = s_cnt[cell0 + 1];
  }
  const int sum = c0 + c1;
  int inc = sum;
#pragma unroll
  for (int d = 1; d < 64; d <<= 1) {
    int v = __shfl_up(inc, d);
    if (lane >= d) inc += v;
  }
  if (lane == 63) s_wave[wv] = inc;
  __syncthreads();  // all counts read before cursor overwrite below
  if (t == 0) {
    int r = 0;
    for (int w = 0; w < 16; ++w) { int v = s_wave[w]; s_wave[w] = r; r += v; }
  }
  __syncthreads();
  const int excl = s_wave[wv] + (inc - sum);
  if (cell0 < NCELLS) {
    const int st0 = pbase + excl;
    const int st1 = pbase + excl + c0;
    meta[cell0 * NPART + p] = ((unsigned)c0 << 16) | (unsigned)st0;
    meta[(cell0 + 1) * NPART + p] = ((unsigned)c1 << 16) | (unsigned)st1;
    s_cnt[cell0] = st0;      // absolute cursor
    s_cnt[cell0 + 1] = st1;
  }
  __syncthreads();

  // Scatter from registers via LDS cursors (absolute slots).
#pragma unroll
  for (int k = 0; k < 4; ++k) {
    const int i = pbase + k * 1024 + t;
    const int slot = atomicAdd(&s_cnt[pc[k]], 1);
    sorted[slot] = make_float4(px[k], py[k], pz[k], __int_as_float(i));
  }
}

__global__ __launch_bounds__(256) void bq_query_kernel(
    const float* __restrict__ p1, const float* __restrict__ p2,
    const unsigned int* __restrict__ meta, const float4* __restrict__ sorted,
    float* __restrict__ out) {
#pragma clang fp contract(off)
  const int lane = threadIdx.x & 63;
  const int wid = threadIdx.x >> 6;
  const int q = blockIdx.x * 4 + wid;

  __shared__ int s_gidx[4][GIDXCAP];    // candidate -> global sorted index
  __shared__ float4 s_hits[4][HITCAP];  // (x, y, z, bitcast idx)

  const float x1 = p1[q * 3 + 0];
  const float y1 = p1[q * 3 + 1];
  const float z1 = p1[q * 3 + 2];
  const float n1 = (x1 * x1 + y1 * y1) + z1 * z1;  // pure rn (contract off)
  const float rsq = (float)(0.08 * 0.08);
  const float prune_thr = 0.006413f;  // rsq*1.002: safe AABB prune bound

  const int cx = min(max((int)(x1 * (float)GDIM), 0), GDIM - 1);
  const int cy = min(max((int)(y1 * (float)GDIM), 0), GDIM - 1);
  const int cz = min(max((int)(z1 * (float)GDIM), 0), GDIM - 1);

  // Lane l (< 54) owns neighbor cell ci = l>>1, partitions (l&1)*2 .. +1.
  // Its 2 runs' metadata is ONE aligned uint2 at meta[cc*4 + (l&1)*2].
  int c0 = 0, c1 = 0;
  int st0 = 0, st1 = 0;
  if (lane < 54) {
    const int ci = lane >> 1;
    const int nx = cx + (ci % 3) - 1;
    const int ny = cy + ((ci / 3) % 3) - 1;
    const int nz = cz + (ci / 9) - 1;
    if (nx >= 0 && nx < GDIM && ny >= 0 && ny < GDIM && nz >= 0 && nz < GDIM) {
      // AABB min-dist^2 prune (conservative; margin >> FP slop).
      const float lx = (float)nx / 12.0f, hx = (float)(nx + 1) / 12.0f;
      const float ly = (float)ny / 12.0f, hy = (float)(ny + 1) / 12.0f;
      const float lz = (float)nz / 12.0f, hz = (float)(nz + 1) / 12.0f;
      const float dx = fmaxf(0.0f, fmaxf(lx - x1, x1 - hx));
      const float dy = fmaxf(0.0f, fmaxf(ly - y1, y1 - hy));
      const float dz = fmaxf(0.0f, fmaxf(lz - z1, z1 - hz));
      const float mind2 = dx * dx + dy * dy + dz * dz;
      if (mind2 <= prune_thr) {
        const int cc = (nz * GDIM + ny) * GDIM + nx;
        const uint2 m2 = *reinterpret_cast<const uint2*>(
            &meta[cc * NPART + (lane & 1) * 2]);
        c0 = (int)(m2.x >> 16); st0 = (int)(m2.x & 0xFFFFu);
        c1 = (int)(m2.y >> 16); st1 = (int)(m2.y & 0xFFFFu);
      }
    }
  }
  // Wave-inclusive scan of per-lane sums -> per-run exclusive prefixes.
  const int lsum = c0 + c1;
  int inc = lsum;
#pragma unroll
  for (int d = 1; d < 64; d <<= 1) {
    int v = __shfl_up(inc, d);
    if (lane >= d) inc += v;
  }
  const int T = __shfl(inc, 63);
  const int pref0 = inc - lsum;
  const int pref1 = pref0 + c0;

  float* __restrict__ mapO = out + (size_t)q * BQ_K;
  float* __restrict__ numO = out + (size_t)BQ_N1 * BQ_K + q;
  float* __restrict__ ptsO =
      out + (size_t)BQ_N1 * BQ_K + BQ_N1 + (size_t)q * BQ_K * 3;

  const bool fast = (T <= GIDXCAP);
  int H = 0;
  if (fast) {
    // Materialize candidate table: each lane writes its 2 runs.
    for (int k = 0; k < c0; ++k) s_gidx[wid][pref0 + k] = st0 + k;
    for (int k = 0; k < c1; ++k) s_gidx[wid][pref1 + k] = st1 + k;

    // Flattened sweep: 1 LDS read + 1 L2 float4 gather per candidate.
    for (int s0 = 0; s0 < T; s0 += 64) {
      const int s = s0 + lane;
      bool within = false;
      float x2 = 0.f, y2 = 0.f, z2 = 0.f;
      int idx = 0;
      if (s < T) {
        const int g = s_gidx[wid][s];
        const float4 pt = sorted[g];
        x2 = pt.x; y2 = pt.y; z2 = pt.z;
        idx = __float_as_int(pt.w);
        // EXACT reference FP chain (round 5) — do not alter.
        const float n2 = (x2 * x2 + y2 * y2) + z2 * z2;
        float dot = x2 * x1;
        dot = __fmaf_rn(y1, y2, dot);
        dot = __fmaf_rn(z1, z2, dot);
        const float nsum = n1 + n2;
        const float twodot = 2.0f * dot;
        const float d2 = nsum - twodot;
        within = (d2 <= rsq);
      }
      const unsigned long long b = __ballot(within);
      if (b) {
        if (within) {
          const int pos = H + (int)__popcll(b & ((1ull << lane) - 1ull));
          if (pos < HITCAP)
            s_hits[wid][pos] = make_float4(x2, y2, z2, __int_as_float(idx));
        }
        H += (int)__popcll(b);
      }
    }
  }

  if (fast && H <= HITCAP) {
    const int nh = min(H, BQ_K);
    float4 h0 = make_float4(0.f, 0.f, 0.f, __int_as_float(0x7fffffff));
    float4 h1 = h0;
    if (lane < H) h0 = s_hits[wid][lane];
    if (lane + 64 < H) h1 = s_hits[wid][lane + 64];
    const int i0 = __float_as_int(h0.w);
    const int i1 = __float_as_int(h1.w);
    int r0 = 0, r1 = 0;
    for (int j = 0; j < H; ++j) {  // broadcast LDS reads
      const int bj = __float_as_int(s_hits[wid][j].w);
      r0 += (bj < i0) ? 1 : 0;
      r1 += (bj < i1) ? 1 : 0;
    }
    if (lane < H && r0 < BQ_K) {
      mapO[r0] = (float)i0;
      ptsO[r0 * 3 + 0] = h0.x;
      ptsO[r0 * 3 + 1] = h0.y;
      ptsO[r0 * 3 + 2] = h0.z;
    }
    if (lane + 64 < H && r1 < BQ_K) {
      mapO[r1] = (float)i1;
      ptsO[r1 * 3 + 0] = h1.x;
      ptsO[r1 * 3 + 1] = h1.y;
      ptsO[r1 * 3 + 2] = h1.z;
    }
    for (int sF = nh + lane; sF < BQ_K; sF += 64) {
      mapO[sF] = 0.0f;
      ptsO[sF * 3 + 0] = 0.0f;
      ptsO[sF * 3 + 1] = 0.0f;
      ptsO[sF * 3 + 2] = 0.0f;
    }
    if (lane == 0) numO[0] = (float)nh;
  } else {
    // Exact sequential fallback (capacity overflow safety net; P ~ 0).
    int filled = 0;
    for (int base = 0; base < BQ_N2; base += 64) {
      const int j = base + lane;
      const float x2 = p2[j * 3 + 0];
      const float y2 = p2[j * 3 + 1];
      const float z2 = p2[j * 3 + 2];
      const float n2 = (x2 * x2 + y2 * y2) + z2 * z2;
      float dot = x2 * x1;
      dot = __fmaf_rn(y1, y2, dot);
      dot = __fmaf_rn(z1, z2, dot);
      const float d2 = (n1 + n2) - 2.0f * dot;
      const bool within = (d2 <= rsq);
      const unsigned long long b = __ballot(within);
      if (b) {
        const int rank = (int)__popcll(b & ((1ull << lane) - 1ull));
        const int slot = filled + rank;
        if (within && slot < BQ_K) {
          mapO[slot] = (float)j;
          ptsO[slot * 3 + 0] = x2;
          ptsO[slot * 3 + 1] = y2;
          ptsO[slot * 3 + 2] = z2;
        }
        filled += (int)__popcll(b);
        if (filled >= BQ_K) { filled = BQ_K; break; }
      }
    }
    for (int sF = filled + lane; sF < BQ_K; sF += 64) {
      mapO[sF] = 0.0f;
      ptsO[sF * 3 + 0] = 0.0f;
      ptsO[sF * 3 + 1] = 0.0f;
      ptsO[sF * 3 + 2] = 0.0f;
    }
    if (lane == 0) numO[0] = (float)filled;
  }
}

// Round-5 brute-force kernel, kept as whole-problem fallback if ws too small.
__global__ __launch_bounds__(256) void bq_seq_kernel(
    const float* __restrict__ p1, const float* __restrict__ p2,
    float* __restrict__ out) {
#pragma clang fp contract(off)
  const int lane = threadIdx.x & 63;
  const int wave = threadIdx.x >> 6;
  const int q = blockIdx.x * 4 + wave;
  const float x1 = p1[q * 3 + 0], y1 = p1[q * 3 + 1], z1 = p1[q * 3 + 2];
  const float n1 = (x1 * x1 + y1 * y1) + z1 * z1;
  const float rsq = (float)(0.08 * 0.08);
  float* mapO = out + (size_t)q * BQ_K;
  float* numO = out + (size_t)BQ_N1 * BQ_K + q;
  float* ptsO = out + (size_t)BQ_N1 * BQ_K + BQ_N1 + (size_t)q * BQ_K * 3;
  int filled = 0;
  for (int base = 0; base < BQ_N2; base += 64) {
    const int j = base + lane;
    const float x2 = p2[j * 3 + 0], y2 = p2[j * 3 + 1], z2 = p2[j * 3 + 2];
    const float n2 = (x2 * x2 + y2 * y2) + z2 * z2;
    float dot = x2 * x1;
    dot = __fmaf_rn(y1, y2, dot);
    dot = __fmaf_rn(z1, z2, dot);
    const float d2 = (n1 + n2) - 2.0f * dot;
    const bool within = (d2 <= rsq);
    const unsigned long long b = __ballot(within);
    if (b) {
      const int rank = (int)__popcll(b & ((1ull << lane) - 1ull));
      const int slot = filled + rank;
      if (within && slot < BQ_K) {
        mapO[slot] = (float)j;
        ptsO[slot * 3 + 0] = x2;
        ptsO[slot * 3 + 1] = y2;
        ptsO[slot * 3 + 2] = z2;
      }
      filled += (int)__popcll(b);
      if (filled >= BQ_K) { filled = BQ_K; break; }
    }
  }
  for (int s = filled + lane; s < BQ_K; s += 64) {
    mapO[s] = 0.0f;
    ptsO[s * 3 + 0] = 0.0f;
    ptsO[s * 3 + 1] = 0.0f;
    ptsO[s * 3 + 2] = 0.0f;
  }
  if (lane == 0) numO[0] = (float)filled;
}

extern "C" void kernel_launch(void* const* d_in, const int* in_sizes, int n_in,
                              void* d_out, int out_size, void* d_ws,
                              size_t ws_size, hipStream_t stream) {
  const float* p1 = (const float*)d_in[0];
  const float* p2 = (const float*)d_in[1];
  float* out = (float*)d_out;

  if (ws_size < (size_t)WS_NEED) {
    bq_seq_kernel<<<BQ_N1 / 4, 256, 0, stream>>>(p1, p2, out);
    return;
  }

  char* ws = (char*)d_ws;
  unsigned int* meta = (unsigned int*)(ws + WS_META_OFF);
  float4* sorted = (float4*)(ws + WS_SORTED_OFF);

  bq_build_kernel<<<NPART, 1024, 0, stream>>>(p2, meta, sorted);
  bq_query_kernel<<<BQ_N1 / 4, 256, 0, stream>>>(p1, p2, meta, sorted, out);
}